// Round 1
// baseline (1437.504 us; speedup 1.0000x reference)
//
#include <hip/hip_runtime.h>
#include <hip/hip_bf16.h>
#include <cstdint>

#define D_MODEL 768
#define N_HEADS 12
#define D_HEAD  64
#define BATCH   2
#define SEQ     2048

// ---------------------------------------------------------------------------
// GEMM (NT): C[M,N] = A[M,K] @ B[N,K]^T + bias[N]
// Tiles: BM=BN=64, BK=32, 256 threads, 4x4 register tile per thread.
// LDS stored K-major transposed (As[kk][row]) with +4 pad so inner-loop
// float4 reads are 16B-aligned and conflict-free (broadcast across 16 lanes).
// MODE 0: scatter epilogue into q/k/v [B,H,T,Dh], q scaled by 1/8.
// MODE 1: plain row-major [M,N] output.
// ---------------------------------------------------------------------------
template<int MODE>
__global__ __launch_bounds__(256)
void gemm_nt_kernel(const float* __restrict__ A, const float* __restrict__ B,
                    const float* __restrict__ bias,
                    float* __restrict__ o0, float* __restrict__ o1, float* __restrict__ o2,
                    int M, int N, int K)
{
    __shared__ float As[32][68];
    __shared__ float Bs[32][68];
    const int tid = threadIdx.x;
    const int tx = tid & 15;
    const int ty = tid >> 4;
    const int bm = blockIdx.x * 64;
    const int bn = blockIdx.y * 64;
    const int r0 = tid >> 3;          // 0..31
    const int c0 = (tid & 7) << 2;    // 0,4,...,28

    const float* Ap0 = A + (size_t)(bm + r0) * K + c0;
    const float* Ap1 = Ap0 + (size_t)32 * K;
    const float* Bp0 = B + (size_t)(bn + r0) * K + c0;
    const float* Bp1 = Bp0 + (size_t)32 * K;

    float acc[4][4] = {};

    for (int k0 = 0; k0 < K; k0 += 32) {
        float4 a0 = *(const float4*)(Ap0 + k0);
        float4 a1 = *(const float4*)(Ap1 + k0);
        float4 b0 = *(const float4*)(Bp0 + k0);
        float4 b1 = *(const float4*)(Bp1 + k0);
        __syncthreads();
        As[c0+0][r0]    = a0.x; As[c0+1][r0]    = a0.y; As[c0+2][r0]    = a0.z; As[c0+3][r0]    = a0.w;
        As[c0+0][r0+32] = a1.x; As[c0+1][r0+32] = a1.y; As[c0+2][r0+32] = a1.z; As[c0+3][r0+32] = a1.w;
        Bs[c0+0][r0]    = b0.x; Bs[c0+1][r0]    = b0.y; Bs[c0+2][r0]    = b0.z; Bs[c0+3][r0]    = b0.w;
        Bs[c0+0][r0+32] = b1.x; Bs[c0+1][r0+32] = b1.y; Bs[c0+2][r0+32] = b1.z; Bs[c0+3][r0+32] = b1.w;
        __syncthreads();
        #pragma unroll
        for (int kk = 0; kk < 32; ++kk) {
            float4 av = *(const float4*)&As[kk][ty << 2];
            float4 bv = *(const float4*)&Bs[kk][tx << 2];
            float a[4] = {av.x, av.y, av.z, av.w};
            float b[4] = {bv.x, bv.y, bv.z, bv.w};
            #pragma unroll
            for (int i = 0; i < 4; ++i)
                #pragma unroll
                for (int j = 0; j < 4; ++j)
                    acc[i][j] = fmaf(a[i], b[j], acc[i][j]);
        }
    }

    const int gn = bn + (tx << 2);
    const int gm = bm + (ty << 2);
    float4 bb = *(const float4*)(bias + gn);

    if (MODE == 0) {
        // qkv scatter: block spans exactly one of {q,k,v} and one head
        const int which = bn / D_MODEL;
        const int c = bn % D_MODEL;
        const int h = c >> 6;
        const int d = (tx << 2);
        const float scale = (which == 0) ? 0.125f : 1.0f;   // fold 1/sqrt(Dh) into q (and its bias)
        float* dst = (which == 0) ? o0 : (which == 1) ? o1 : o2;
        #pragma unroll
        for (int i = 0; i < 4; ++i) {
            const int m = gm + i;
            const int b = m >> 11;      // /SEQ
            const int t = m & 2047;     // %SEQ
            float4 v;
            v.x = (acc[i][0] + bb.x) * scale;
            v.y = (acc[i][1] + bb.y) * scale;
            v.z = (acc[i][2] + bb.z) * scale;
            v.w = (acc[i][3] + bb.w) * scale;
            *(float4*)(dst + ((((size_t)b * N_HEADS + h) * SEQ + t) << 6) + d) = v;
        }
    } else {
        #pragma unroll
        for (int i = 0; i < 4; ++i) {
            float4 v;
            v.x = acc[i][0] + bb.x;
            v.y = acc[i][1] + bb.y;
            v.z = acc[i][2] + bb.z;
            v.w = acc[i][3] + bb.w;
            *(float4*)(o0 + (size_t)(gm + i) * N + gn) = v;
        }
    }
}

// ---------------------------------------------------------------------------
// Flash attention (fp32, causal). One wave per 64-row Q tile.
// Lane r owns q-row (qi*64 + r): Q (64 f32) and O (64 f32) live in registers.
// K/V 64x64 tiles staged in LDS; inner reads are wave-broadcast (same addr
// across all lanes) -> no bank conflicts. Online softmax with deferred
// rescale (threshold 8: exp stays bounded, rescale essentially never fires).
// Output written in [B,T,H,Dh] = [B,T,C] layout for the proj GEMM.
// ---------------------------------------------------------------------------
__global__ __launch_bounds__(64)
void flash_attn_kernel(const float* __restrict__ qb, const float* __restrict__ kb,
                       const float* __restrict__ vb, float* __restrict__ ob)
{
    __shared__ float Ks[64][68];
    __shared__ float Vs[64][68];
    const int lane = threadIdx.x;
    const int qi = (int)gridDim.x - 1 - (int)blockIdx.x;  // heavy tiles first
    const int bh = blockIdx.y;                            // b*N_HEADS + h
    const int qrow = (qi << 6) + lane;

    const float* qp = qb + (((size_t)bh * SEQ + qrow) << 6);
    float4 qv[16];
    #pragma unroll
    for (int d4 = 0; d4 < 16; ++d4) qv[d4] = ((const float4*)qp)[d4];

    float4 O[16];
    #pragma unroll
    for (int d4 = 0; d4 < 16; ++d4) O[d4] = make_float4(0.f, 0.f, 0.f, 0.f);
    float m = 0.f, l = 0.f;

    for (int kt = 0; kt <= qi; ++kt) {
        const float4* kp = (const float4*)(kb + (((size_t)bh * SEQ + (kt << 6) + lane) << 6));
        const float4* vp = (const float4*)(vb + (((size_t)bh * SEQ + (kt << 6) + lane) << 6));
        __syncthreads();
        #pragma unroll
        for (int d4 = 0; d4 < 16; ++d4) *(float4*)&Ks[lane][d4 << 2] = kp[d4];
        #pragma unroll
        for (int d4 = 0; d4 < 16; ++d4) *(float4*)&Vs[lane][d4 << 2] = vp[d4];
        __syncthreads();
        const int jmax = (kt == qi) ? lane : 63;
        #pragma unroll 1
        for (int j = 0; j < 64; ++j) {
            const float4* kr = (const float4*)&Ks[j][0];
            float s0 = 0.f, s1 = 0.f, s2 = 0.f, s3 = 0.f;
            #pragma unroll
            for (int d4 = 0; d4 < 16; ++d4) {
                float4 kv = kr[d4];
                s0 = fmaf(qv[d4].x, kv.x, s0);
                s1 = fmaf(qv[d4].y, kv.y, s1);
                s2 = fmaf(qv[d4].z, kv.z, s2);
                s3 = fmaf(qv[d4].w, kv.w, s3);
            }
            float s = (s0 + s1) + (s2 + s3);
            if (j > jmax) s = -1e30f;               // causal mask (exp -> 0)
            if (s > m + 8.f) {                      // deferred rescale (rare)
                const float sc = __expf(m - s);
                l *= sc;
                #pragma unroll
                for (int d4 = 0; d4 < 16; ++d4) {
                    O[d4].x *= sc; O[d4].y *= sc; O[d4].z *= sc; O[d4].w *= sc;
                }
                m = s;
            }
            const float p = __expf(s - m);
            l += p;
            const float4* vr = (const float4*)&Vs[j][0];
            #pragma unroll
            for (int d4 = 0; d4 < 16; ++d4) {
                float4 vv = vr[d4];
                O[d4].x = fmaf(p, vv.x, O[d4].x);
                O[d4].y = fmaf(p, vv.y, O[d4].y);
                O[d4].z = fmaf(p, vv.z, O[d4].z);
                O[d4].w = fmaf(p, vv.w, O[d4].w);
            }
        }
    }

    const float inv = 1.0f / l;
    const int b = bh / N_HEADS;
    const int h = bh % N_HEADS;
    float* op = ob + ((size_t)b * SEQ + qrow) * D_MODEL + (h << 6);
    #pragma unroll
    for (int d4 = 0; d4 < 16; ++d4) {
        float4 v = O[d4];
        v.x *= inv; v.y *= inv; v.z *= inv; v.w *= inv;
        ((float4*)op)[d4] = v;
    }
}

// ---------------------------------------------------------------------------
extern "C" void kernel_launch(void* const* d_in, const int* in_sizes, int n_in,
                              void* d_out, int out_size, void* d_ws, size_t ws_size,
                              hipStream_t stream)
{
    const float* x      = (const float*)d_in[0];
    // d_in[1] = mask: exactly triu(k=1) causal; applied analytically in-kernel.
    const float* W_qkv  = (const float*)d_in[2];
    const float* b_qkv  = (const float*)d_in[3];
    const float* W_proj = (const float*)d_in[4];
    const float* b_proj = (const float*)d_in[5];
    float* out = (float*)d_out;

    const size_t per = (size_t)BATCH * N_HEADS * SEQ * D_HEAD;  // 3,145,728 floats
    float* q  = (float*)d_ws;
    float* k  = q + per;
    float* v  = k + per;
    float* ao = v + per;   // attention output, [B,T,C]

    // 1) qkv = x @ W_qkv^T + b  -> scatter to q/k/v [B,H,T,Dh] (q pre-scaled)
    gemm_nt_kernel<0><<<dim3(64, 36), 256, 0, stream>>>(
        x, W_qkv, b_qkv, q, k, v, BATCH * SEQ, 3 * D_MODEL, D_MODEL);

    // 2) causal flash attention -> ao [B,T,C]
    flash_attn_kernel<<<dim3(SEQ / 64, BATCH * N_HEADS), 64, 0, stream>>>(q, k, v, ao);

    // 3) out = ao @ W_proj^T + b
    gemm_nt_kernel<1><<<dim3(64, 12), 256, 0, stream>>>(
        ao, W_proj, b_proj, out, nullptr, nullptr, BATCH * SEQ, D_MODEL, D_MODEL);
}

// Round 2
// 546.665 us; speedup vs baseline: 2.6296x; 2.6296x over previous
//
#include <hip/hip_runtime.h>
#include <hip/hip_bf16.h>
#include <cstdint>

#define D_MODEL 768
#define N_HEADS 12
#define D_HEAD  64
#define BATCH   2
#define SEQ     2048

typedef float f32x4 __attribute__((ext_vector_type(4)));
typedef short s16x8 __attribute__((ext_vector_type(8)));
typedef short s16x4 __attribute__((ext_vector_type(4)));

static __device__ __forceinline__ unsigned short f2bf(float f) {
    union { float f; unsigned int u; } c; c.f = f;
    unsigned int u = c.u;
    u += 0x7fffu + ((u >> 16) & 1u);            // RNE
    return (unsigned short)(u >> 16);
}

static __device__ __forceinline__ f32x4 mfma16_bf16(s16x4 a, s16x4 b, f32x4 c) {
#if __has_builtin(__builtin_amdgcn_mfma_f32_16x16x16bf16_1k)
    return __builtin_amdgcn_mfma_f32_16x16x16bf16_1k(a, b, c, 0, 0, 0);
#else
    asm volatile("v_mfma_f32_16x16x16_bf16 %0, %1, %2, %0" : "+v"(c) : "v"(a), "v"(b));
    return c;
#endif
}

// ---------------------------------------------------------------------------
// GEMM (NT): C[M,N] = A[M,K] @ B[N,K]^T + bias[N]   (fp32 VALU, 64x64x32 tile)
// MODE 0: epilogue emits bf16 q (scaled 1/8) [B,H,T,64], bf16 k [B,H,T,64],
//         bf16 V^T [B,H,64,T].
// MODE 1: plain fp32 row-major [M,N].
// ---------------------------------------------------------------------------
template<int MODE>
__global__ __launch_bounds__(256)
void gemm_nt_kernel(const float* __restrict__ A, const float* __restrict__ B,
                    const float* __restrict__ bias, float* __restrict__ outf,
                    unsigned short* __restrict__ qo, unsigned short* __restrict__ ko,
                    unsigned short* __restrict__ vt,
                    int M, int N, int K)
{
    __shared__ float As[32][68];
    __shared__ float Bs[32][68];
    const int tid = threadIdx.x;
    const int tx = tid & 15;
    const int ty = tid >> 4;
    const int bm = blockIdx.x * 64;
    const int bn = blockIdx.y * 64;
    const int r0 = tid >> 3;          // 0..31
    const int c0 = (tid & 7) << 2;    // 0,4,...,28

    const float* Ap0 = A + (size_t)(bm + r0) * K + c0;
    const float* Ap1 = Ap0 + (size_t)32 * K;
    const float* Bp0 = B + (size_t)(bn + r0) * K + c0;
    const float* Bp1 = Bp0 + (size_t)32 * K;

    float acc[4][4] = {};

    for (int k0 = 0; k0 < K; k0 += 32) {
        float4 a0 = *(const float4*)(Ap0 + k0);
        float4 a1 = *(const float4*)(Ap1 + k0);
        float4 b0 = *(const float4*)(Bp0 + k0);
        float4 b1 = *(const float4*)(Bp1 + k0);
        __syncthreads();
        As[c0+0][r0]    = a0.x; As[c0+1][r0]    = a0.y; As[c0+2][r0]    = a0.z; As[c0+3][r0]    = a0.w;
        As[c0+0][r0+32] = a1.x; As[c0+1][r0+32] = a1.y; As[c0+2][r0+32] = a1.z; As[c0+3][r0+32] = a1.w;
        Bs[c0+0][r0]    = b0.x; Bs[c0+1][r0]    = b0.y; Bs[c0+2][r0]    = b0.z; Bs[c0+3][r0]    = b0.w;
        Bs[c0+0][r0+32] = b1.x; Bs[c0+1][r0+32] = b1.y; Bs[c0+2][r0+32] = b1.z; Bs[c0+3][r0+32] = b1.w;
        __syncthreads();
        #pragma unroll
        for (int kk = 0; kk < 32; ++kk) {
            float4 av = *(const float4*)&As[kk][ty << 2];
            float4 bv = *(const float4*)&Bs[kk][tx << 2];
            float a[4] = {av.x, av.y, av.z, av.w};
            float b[4] = {bv.x, bv.y, bv.z, bv.w};
            #pragma unroll
            for (int i = 0; i < 4; ++i)
                #pragma unroll
                for (int j = 0; j < 4; ++j)
                    acc[i][j] = fmaf(a[i], b[j], acc[i][j]);
        }
    }

    const int gn = bn + (tx << 2);
    const int gm = bm + (ty << 2);
    float4 bb = *(const float4*)(bias + gn);

    if (MODE == 0) {
        const int which = bn / D_MODEL;       // 0=q 1=k 2=v
        const int cc = bn % D_MODEL;
        const int h = cc >> 6;
        const int d = tx << 2;                // dh base (0..60)
        if (which == 2) {
            // V^T store: [B,H,64,T] bf16
            const int b = gm >> 11, t0 = gm & 2047;
            const size_t base = (size_t)(b * N_HEADS + h) * 64;
            const float bias4[4] = {bb.x, bb.y, bb.z, bb.w};
            #pragma unroll
            for (int j = 0; j < 4; ++j) {
                ushort4 pv;
                pv.x = f2bf(acc[0][j] + bias4[j]);
                pv.y = f2bf(acc[1][j] + bias4[j]);
                pv.z = f2bf(acc[2][j] + bias4[j]);
                pv.w = f2bf(acc[3][j] + bias4[j]);
                *(ushort4*)(vt + (base + d + j) * SEQ + t0) = pv;
            }
        } else {
            unsigned short* dst = (which == 0) ? qo : ko;
            const float scale = (which == 0) ? 0.125f : 1.0f;  // fold 1/sqrt(Dh) into q
            #pragma unroll
            for (int i = 0; i < 4; ++i) {
                const int mrow = gm + i;
                const int b = mrow >> 11, t = mrow & 2047;
                ushort4 pv;
                pv.x = f2bf((acc[i][0] + bb.x) * scale);
                pv.y = f2bf((acc[i][1] + bb.y) * scale);
                pv.z = f2bf((acc[i][2] + bb.z) * scale);
                pv.w = f2bf((acc[i][3] + bb.w) * scale);
                *(ushort4*)(dst + ((((size_t)b * N_HEADS + h) * SEQ + t) << 6) + d) = pv;
            }
        }
    } else {
        #pragma unroll
        for (int i = 0; i < 4; ++i) {
            float4 v;
            v.x = acc[i][0] + bb.x;
            v.y = acc[i][1] + bb.y;
            v.z = acc[i][2] + bb.z;
            v.w = acc[i][3] + bb.w;
            *(float4*)(outf + (size_t)(gm + i) * N + gn) = v;
        }
    }
}

// ---------------------------------------------------------------------------
// MFMA flash attention (bf16 inputs, fp32 accum, causal).
// One wave per 16 q-rows. Swapped QK^T: S^T = mfma_16x16x32(A=K, B=Q) so lane
// holds P[q=lane&15][kv=(lane>>4)*4+r] — exactly the A-frag layout of the
// 16x16x16 PV mfma (no cross-lane data movement). V consumed pre-transposed
// [B,H,64,T] so PV B-frags are contiguous 8B loads. No LDS, no barriers;
// K/V frags software-pipelined one kv-tile ahead. Deferred-rescale online
// softmax (THR=8, rescale ~never taken). Output fp32 [B,T,C].
// ---------------------------------------------------------------------------
__global__ __launch_bounds__(64)
void mfma_attn_kernel(const unsigned short* __restrict__ qb,
                      const unsigned short* __restrict__ kb,
                      const unsigned short* __restrict__ vtb,
                      float* __restrict__ ob)
{
    const int lane = threadIdx.x;
    const int qt = (int)gridDim.x - 1 - (int)blockIdx.x;  // heavy tiles first
    const int bh = blockIdx.y;
    const int g = lane >> 4;            // lane group 0..3
    const int c = lane & 15;            // col lane 0..15
    const int qbase = g << 2;           // O-row base q_local
    const int q0 = qt << 4;

    // Q B-frags (held for whole wave): Q[q0+c][k-chunk]
    const unsigned short* qrow = qb + ((size_t)bh * SEQ + q0 + c) * 64 + (g << 3);
    const s16x8 qa0 = *(const s16x8*)(qrow);
    const s16x8 qa1 = *(const s16x8*)(qrow + 32);

    const unsigned short* kbase = kb + (size_t)bh * SEQ * 64 + (size_t)c * 64 + (g << 3);
    const unsigned short* vbase = vtb + ((size_t)bh * 64 + c) * SEQ + (g << 2);

    f32x4 o0 = {0,0,0,0}, o1 = {0,0,0,0}, o2 = {0,0,0,0}, o3 = {0,0,0,0};
    float m = 0.f, l = 0.f;

    // preload tile 0
    s16x8 ka0 = *(const s16x8*)(kbase);
    s16x8 ka1 = *(const s16x8*)(kbase + 32);
    s16x4 vb0 = *(const s16x4*)(vbase);
    s16x4 vb1 = *(const s16x4*)(vbase + 16 * SEQ);
    s16x4 vb2 = *(const s16x4*)(vbase + 32 * SEQ);
    s16x4 vb3 = *(const s16x4*)(vbase + 48 * SEQ);

    for (int kt = 0; kt <= qt; ++kt) {
        s16x8 nka0, nka1; s16x4 nvb0, nvb1, nvb2, nvb3;
        if (kt < qt) {                                  // prefetch next tile
            const unsigned short* kp = kbase + (size_t)(kt + 1) * 16 * 64;
            nka0 = *(const s16x8*)(kp);
            nka1 = *(const s16x8*)(kp + 32);
            const unsigned short* vp = vbase + (kt + 1) * 16;
            nvb0 = *(const s16x4*)(vp);
            nvb1 = *(const s16x4*)(vp + 16 * SEQ);
            nvb2 = *(const s16x4*)(vp + 32 * SEQ);
            nvb3 = *(const s16x4*)(vp + 48 * SEQ);
        }

        // S^T tile: rows kv (tile-local), cols q
        f32x4 s4 = {0,0,0,0};
        s4 = __builtin_amdgcn_mfma_f32_16x16x32_bf16(ka0, qa0, s4, 0, 0, 0);
        s4 = __builtin_amdgcn_mfma_f32_16x16x32_bf16(ka1, qa1, s4, 0, 0, 0);
        float s0 = s4[0], s1 = s4[1], s2 = s4[2], s3 = s4[3];
        if (kt == qt) {                                 // causal diagonal tile
            if (qbase + 0 > c) s0 = -1e30f;
            if (qbase + 1 > c) s1 = -1e30f;
            if (qbase + 2 > c) s2 = -1e30f;
            if (qbase + 3 > c) s3 = -1e30f;
        }

        float pmax = fmaxf(fmaxf(s0, s1), fmaxf(s2, s3));
        pmax = fmaxf(pmax, __shfl_xor(pmax, 16));
        pmax = fmaxf(pmax, __shfl_xor(pmax, 32));
        if (__any(pmax > m + 8.f)) {                    // deferred rescale (rare)
            const float mn = fmaxf(m, pmax);
            const float sc = __expf(m - mn);
            l *= sc;
            f32x4 scv;
            scv[0] = __shfl(sc, qbase + 0);
            scv[1] = __shfl(sc, qbase + 1);
            scv[2] = __shfl(sc, qbase + 2);
            scv[3] = __shfl(sc, qbase + 3);
            o0 *= scv; o1 *= scv; o2 *= scv; o3 *= scv;
            m = mn;
        }
        const float p0 = __expf(s0 - m), p1 = __expf(s1 - m);
        const float p2 = __expf(s2 - m), p3 = __expf(s3 - m);
        float part = (p0 + p1) + (p2 + p3);
        part += __shfl_xor(part, 16);
        part += __shfl_xor(part, 32);
        l += part;

        s16x4 pa;
        pa[0] = (short)f2bf(p0); pa[1] = (short)f2bf(p1);
        pa[2] = (short)f2bf(p2); pa[3] = (short)f2bf(p3);

        o0 = mfma16_bf16(pa, vb0, o0);
        o1 = mfma16_bf16(pa, vb1, o1);
        o2 = mfma16_bf16(pa, vb2, o2);
        o3 = mfma16_bf16(pa, vb3, o3);

        ka0 = nka0; ka1 = nka1;
        vb0 = nvb0; vb1 = nvb1; vb2 = nvb2; vb3 = nvb3;
    }

    const float inv = 1.0f / l;                         // held at q = c
    const int b = bh / N_HEADS, h = bh % N_HEADS;
    float* orow = ob + ((size_t)b * SEQ + q0) * D_MODEL + (h << 6) + c;
    #pragma unroll
    for (int r = 0; r < 4; ++r) {
        const float iv = __shfl(inv, qbase + r);
        float* pr = orow + (size_t)(qbase + r) * D_MODEL;
        pr[0]  = o0[r] * iv;
        pr[16] = o1[r] * iv;
        pr[32] = o2[r] * iv;
        pr[48] = o3[r] * iv;
    }
}

// ---------------------------------------------------------------------------
extern "C" void kernel_launch(void* const* d_in, const int* in_sizes, int n_in,
                              void* d_out, int out_size, void* d_ws, size_t ws_size,
                              hipStream_t stream)
{
    const float* x      = (const float*)d_in[0];
    // d_in[1] = mask: exactly triu(k=1) causal; applied analytically in-kernel.
    const float* W_qkv  = (const float*)d_in[2];
    const float* b_qkv  = (const float*)d_in[3];
    const float* W_proj = (const float*)d_in[4];
    const float* b_proj = (const float*)d_in[5];
    float* out = (float*)d_out;

    const size_t per = (size_t)BATCH * N_HEADS * SEQ * D_HEAD;  // 3,145,728
    unsigned short* qbf = (unsigned short*)d_ws;
    unsigned short* kbf = qbf + per;
    unsigned short* vtb = kbf + per;
    float* ao = (float*)(vtb + per);    // [B,T,C] fp32, 16B-aligned offset

    // 1) qkv = x @ W_qkv^T + b  -> bf16 q(scaled)/k [B,H,T,64], bf16 V^T [B,H,64,T]
    gemm_nt_kernel<0><<<dim3(64, 36), 256, 0, stream>>>(
        x, W_qkv, b_qkv, nullptr, qbf, kbf, vtb, BATCH * SEQ, 3 * D_MODEL, D_MODEL);

    // 2) causal MFMA flash attention -> ao [B,T,C]
    mfma_attn_kernel<<<dim3(SEQ / 16, BATCH * N_HEADS), 64, 0, stream>>>(qbf, kbf, vtb, ao);

    // 3) out = ao @ W_proj^T + b
    gemm_nt_kernel<1><<<dim3(64, 12), 256, 0, stream>>>(
        ao, W_proj, b_proj, out, nullptr, nullptr, nullptr, BATCH * SEQ, D_MODEL, D_MODEL);
}

// Round 3
// 301.017 us; speedup vs baseline: 4.7755x; 1.8161x over previous
//
#include <hip/hip_runtime.h>
#include <hip/hip_bf16.h>
#include <cstdint>

#define D_MODEL 768
#define N_HEADS 12
#define D_HEAD  64
#define BATCH   2
#define SEQ     2048
#define SCALE_Q 0.125f   // 1/sqrt(D_HEAD), folded into q at QKV epilogue

typedef float f32x4 __attribute__((ext_vector_type(4)));
typedef short s16x8 __attribute__((ext_vector_type(8)));
typedef short s16x4 __attribute__((ext_vector_type(4)));
typedef unsigned short u16;

static __device__ __forceinline__ u16 f2bf(float f) {
    union { float f; unsigned int u; } c; c.f = f;
    unsigned int u = c.u;
    u += 0x7fffu + ((u >> 16) & 1u);            // RNE
    return (u16)(u >> 16);
}

static __device__ __forceinline__ f32x4 mfma16x32(s16x8 a, s16x8 b, f32x4 c) {
    return __builtin_amdgcn_mfma_f32_16x16x32_bf16(a, b, c, 0, 0, 0);
}
static __device__ __forceinline__ f32x4 mfma16x16(s16x4 a, s16x4 b, f32x4 c) {
#if __has_builtin(__builtin_amdgcn_mfma_f32_16x16x16bf16_1k)
    return __builtin_amdgcn_mfma_f32_16x16x16bf16_1k(a, b, c, 0, 0, 0);
#else
    asm volatile("v_mfma_f32_16x16x16_bf16 %0, %1, %2, %0" : "+v"(c) : "v"(a), "v"(b));
    return c;
#endif
}
// async global->LDS, 16B per lane; LDS dest must be linear in lane order.
static __device__ __forceinline__ void gload_lds16(const void* g, void* l) {
    __builtin_amdgcn_global_load_lds(
        (const __attribute__((address_space(1))) unsigned int*)g,
        (__attribute__((address_space(3))) unsigned int*)l, 16, 0, 0);
}

// ---------------------------------------------------------------------------
// fp32 -> bf16 convert for x, W_qkv, W_proj (one launch, 4 elems/thread)
// ---------------------------------------------------------------------------
__global__ __launch_bounds__(256)
void cvt3_kernel(const float* __restrict__ s0, u16* __restrict__ d0, int n0,
                 const float* __restrict__ s1, u16* __restrict__ d1, int n1,
                 const float* __restrict__ s2, u16* __restrict__ d2, int n2)
{
    const int idx4 = (blockIdx.x * 256 + threadIdx.x) * 4;
    const float* s; u16* d; int local;
    if (idx4 < n0)           { s = s0; d = d0; local = idx4; }
    else if (idx4 < n0 + n1) { s = s1; d = d1; local = idx4 - n0; }
    else if (idx4 < n0 + n1 + n2) { s = s2; d = d2; local = idx4 - n0 - n1; }
    else return;
    float4 v = *(const float4*)(s + local);
    ushort4 o;
    o.x = f2bf(v.x); o.y = f2bf(v.y); o.z = f2bf(v.z); o.w = f2bf(v.w);
    *(ushort4*)(d + local) = o;
}

// ---------------------------------------------------------------------------
// bf16 MFMA GEMM (NT): C[M,N] = A[M,K] @ B[N,K]^T + bias[N]
// BKx = 32. 256 threads = 4 waves (2x2), wave tile (BM/2)x(BN/2), 16x16x32 mfma.
// Staging: global_load_lds w16 (linear LDS dest); bank-conflict fix via the
// both-sides XOR swizzle (chunk' = chunk ^ ((row>>1)&3)) applied to the GLOBAL
// source chunk on write and to the ds_read address on read (rule #21).
// MODE 0: QKV epilogue -> bf16 q (x SCALE_Q) [B,H,T,64], k [B,H,T,64], V^T [B,H,64,T]
// MODE 1: fp32 row-major [M,N] output.
// ---------------------------------------------------------------------------
template<int BM, int BN, int MODE>
__global__ __launch_bounds__(256)
void mfma_gemm_kernel(const u16* __restrict__ A, const u16* __restrict__ Bw,
                      const float* __restrict__ bias,
                      float* __restrict__ outf,
                      u16* __restrict__ qo, u16* __restrict__ ko, u16* __restrict__ vt,
                      int M, int N, int K)
{
    constexpr int BK = 32;
    __shared__ u16 As[BM * BK];
    __shared__ u16 Bs[BN * BK];
    const int tid = threadIdx.x;
    const int wave = tid >> 6, lane = tid & 63;
    const int wr = wave >> 1, wc = wave & 1;
    constexpr int WM = BM / 2, WN = BN / 2, FI = WM / 16, FJ = WN / 16;
    const int g = lane >> 4, c = lane & 15;
    const int bm = blockIdx.x * BM, bn = blockIdx.y * BN;

    f32x4 acc[FI][FJ] = {};

    constexpr int IA = (BM * BK * 2) / (256 * 16);   // 16B issues/thread for A
    constexpr int IB = (BN * BK * 2) / (256 * 16);

    // staging source pointers (swizzled chunk), computed once
    const u16* asrc[IA]; const u16* bsrc[IB];
    #pragma unroll
    for (int i = 0; i < IA; ++i) {
        const int idx = tid + i * 256;               // 16B chunk id (linear LDS)
        const int row = idx >> 2, kc = idx & 3;
        const int kcs = kc ^ ((row >> 1) & 3);       // inverse swizzle on source
        asrc[i] = A + (size_t)(bm + row) * K + kcs * 8;
    }
    #pragma unroll
    for (int i = 0; i < IB; ++i) {
        const int idx = tid + i * 256;
        const int row = idx >> 2, kc = idx & 3;
        const int kcs = kc ^ ((row >> 1) & 3);
        bsrc[i] = Bw + (size_t)(bn + row) * K + kcs * 8;
    }
    const int gsw = g ^ ((c >> 1) & 3);              // swizzled read chunk

    for (int k0 = 0; k0 < K; k0 += BK) {
        if (k0) __syncthreads();                     // all reads of prev tile done
        #pragma unroll
        for (int i = 0; i < IA; ++i) gload_lds16(asrc[i] + k0, &As[(tid + i * 256) * 8]);
        #pragma unroll
        for (int i = 0; i < IB; ++i) gload_lds16(bsrc[i] + k0, &Bs[(tid + i * 256) * 8]);
        __syncthreads();                             // vmcnt drained by compiler

        s16x8 af[FI], bf[FJ];
        #pragma unroll
        for (int i = 0; i < FI; ++i)
            af[i] = *(const s16x8*)&As[(wr * WM + i * 16 + c) * BK + gsw * 8];
        #pragma unroll
        for (int j = 0; j < FJ; ++j)
            bf[j] = *(const s16x8*)&Bs[(wc * WN + j * 16 + c) * BK + gsw * 8];
        #pragma unroll
        for (int i = 0; i < FI; ++i)
            #pragma unroll
            for (int j = 0; j < FJ; ++j)
                acc[i][j] = mfma16x32(af[i], bf[j], acc[i][j]);
    }

    // D layout: lane(g,c) reg r = C[row0 + g*4 + r][col=c-offset]
    if (MODE == 1) {
        #pragma unroll
        for (int j = 0; j < FJ; ++j) {
            const int col = bn + wc * WN + j * 16 + c;
            const float bv = bias[col];
            #pragma unroll
            for (int i = 0; i < FI; ++i) {
                const int row0 = bm + wr * WM + i * 16 + g * 4;
                #pragma unroll
                for (int r = 0; r < 4; ++r)
                    outf[(size_t)(row0 + r) * N + col] = acc[i][j][r] + bv;
            }
        }
    } else {
        const int which = bn / D_MODEL;              // 0=q 1=k 2=v (BN=128 | 768)
        #pragma unroll
        for (int j = 0; j < FJ; ++j) {
            const int gcol = bn + wc * WN + j * 16 + c;
            const float bv = bias[gcol];
            const int scol = gcol - which * D_MODEL;
            const int h = scol >> 6, d = scol & 63;
            if (which == 2) {
                #pragma unroll
                for (int i = 0; i < FI; ++i) {
                    const int row0 = bm + wr * WM + i * 16 + g * 4;
                    const int b = row0 >> 11, t = row0 & 2047;
                    ushort4 pv;
                    pv.x = f2bf(acc[i][j][0] + bv);
                    pv.y = f2bf(acc[i][j][1] + bv);
                    pv.z = f2bf(acc[i][j][2] + bv);
                    pv.w = f2bf(acc[i][j][3] + bv);
                    *(ushort4*)(vt + ((size_t)(b * N_HEADS + h) * 64 + d) * SEQ + t) = pv;
                }
            } else {
                u16* dst = (which == 0) ? qo : ko;
                const float sc = (which == 0) ? SCALE_Q : 1.0f;
                #pragma unroll
                for (int i = 0; i < FI; ++i) {
                    const int row0 = bm + wr * WM + i * 16 + g * 4;
                    const int b = row0 >> 11, t = row0 & 2047;
                    #pragma unroll
                    for (int r = 0; r < 4; ++r)
                        dst[(((size_t)(b * N_HEADS + h) * SEQ + t + r) << 6) + d] =
                            f2bf((acc[i][j][r] + bv) * sc);
                }
            }
        }
    }
}

// ---------------------------------------------------------------------------
// MFMA flash attention (bf16, fp32 accum, causal). One wave per 16 q-rows.
// Swapped QK^T (S^T = mfma(K,Q)): lane(g,c) holds P[q=c][kv=g*4+r] == exactly
// the 16x16x16 PV A-frag. Steady state has NO cross-lane ops: per-lane m
// (consistent across groups; only changes on the __any-gated rare rescale),
// per-lane partial l (reduced once at the end). KVBLK=32: two independent
// 16-kv chains per iteration for ILP; register prefetch one chunk ahead.
// Output bf16 [B,T,C] (feeds proj GEMM directly).
// ---------------------------------------------------------------------------
__global__ __launch_bounds__(64)
void mfma_attn_kernel(const u16* __restrict__ qb, const u16* __restrict__ kb,
                      const u16* __restrict__ vtb, u16* __restrict__ ob)
{
    const int lane = threadIdx.x;
    const int qt = (int)gridDim.x - 1 - (int)blockIdx.x;   // heavy tiles first
    const int bh = blockIdx.y;
    const int g = lane >> 4, c = lane & 15;
    const int rbase = g << 2;          // kv-row base in-tile; also o-row base
    const int q0 = qt << 4;

    const u16* qrow = qb + ((size_t)bh * SEQ + q0 + c) * 64 + g * 8;
    const s16x8 qa0 = *(const s16x8*)(qrow);
    const s16x8 qa1 = *(const s16x8*)(qrow + 32);

    const u16* kbase = kb + (size_t)bh * SEQ * 64 + c * 64 + g * 8;
    const u16* vbase = vtb + ((size_t)bh * 64 + c) * SEQ + g * 4;

    f32x4 o0 = {0,0,0,0}, o1 = {0,0,0,0}, o2 = {0,0,0,0}, o3 = {0,0,0,0};
    float m = 0.f, l = 0.f;

#define LOADK(t16, KA0, KA1) { const u16* kp = kbase + (size_t)(t16) * (16 * 64); \
    KA0 = *(const s16x8*)kp; KA1 = *(const s16x8*)(kp + 32); }
#define LOADV(t16, V0, V1, V2, V3) { const u16* vp = vbase + (t16) * 16;          \
    V0 = *(const s16x4*)vp;              V1 = *(const s16x4*)(vp + 16 * SEQ);     \
    V2 = *(const s16x4*)(vp + 32 * SEQ); V3 = *(const s16x4*)(vp + 48 * SEQ); }

#define TILE(KA0, KA1, V0, V1, V2, V3, MASKED) {                                  \
    f32x4 sa = {0,0,0,0}, sb = {0,0,0,0};                                         \
    sa = mfma16x32(KA0, qa0, sa);                                                 \
    sb = mfma16x32(KA1, qa1, sb);                                                 \
    f32x4 s = sa + sb;                                                            \
    if (MASKED) {                                                                 \
        if (rbase + 0 > c) s[0] = -1e30f;                                         \
        if (rbase + 1 > c) s[1] = -1e30f;                                         \
        if (rbase + 2 > c) s[2] = -1e30f;                                         \
        if (rbase + 3 > c) s[3] = -1e30f;                                         \
    }                                                                             \
    float pmax = fmaxf(fmaxf(s[0], s[1]), fmaxf(s[2], s[3]));                     \
    if (__any(pmax > m + 8.f)) {               /* rare: full rescale */           \
        pmax = fmaxf(pmax, __shfl_xor(pmax, 16));                                 \
        pmax = fmaxf(pmax, __shfl_xor(pmax, 32));                                 \
        const float mn = fmaxf(m, pmax);                                          \
        const float scr = __expf(m - mn);                                         \
        l *= scr;                                                                 \
        f32x4 scv;                                                                \
        scv[0] = __shfl(scr, rbase + 0);                                          \
        scv[1] = __shfl(scr, rbase + 1);                                          \
        scv[2] = __shfl(scr, rbase + 2);                                          \
        scv[3] = __shfl(scr, rbase + 3);                                          \
        o0 *= scv; o1 *= scv; o2 *= scv; o3 *= scv;                               \
        m = mn;                                                                   \
    }                                                                             \
    const float p0 = __expf(s[0] - m), p1 = __expf(s[1] - m);                     \
    const float p2 = __expf(s[2] - m), p3 = __expf(s[3] - m);                     \
    l += (p0 + p1) + (p2 + p3);                                                   \
    s16x4 pa;                                                                     \
    pa[0] = (short)f2bf(p0); pa[1] = (short)f2bf(p1);                             \
    pa[2] = (short)f2bf(p2); pa[3] = (short)f2bf(p3);                             \
    o0 = mfma16x16(pa, V0, o0);                                                   \
    o1 = mfma16x16(pa, V1, o1);                                                   \
    o2 = mfma16x16(pa, V2, o2);                                                   \
    o3 = mfma16x16(pa, V3, o3);                                                   \
}

    const int nfull = qt >> 1;                     // full 32-kv chunks
    s16x8 kaA0, kaA1, kaB0, kaB1, nkA0, nkA1, nkB0, nkB1;
    s16x4 vA0, vA1, vA2, vA3, vB0, vB1, vB2, vB3;
    s16x4 nvA0, nvA1, nvA2, nvA3, nvB0, nvB1, nvB2, nvB3;

    if (nfull > 0) {
        LOADK(0, kaA0, kaA1); LOADV(0, vA0, vA1, vA2, vA3);
        LOADK(1, kaB0, kaB1); LOADV(1, vB0, vB1, vB2, vB3);
    }
    for (int ch = 0; ch < nfull; ++ch) {
        if (ch + 1 < nfull) {                      // prefetch next chunk
            LOADK(2 * ch + 2, nkA0, nkA1); LOADV(2 * ch + 2, nvA0, nvA1, nvA2, nvA3);
            LOADK(2 * ch + 3, nkB0, nkB1); LOADV(2 * ch + 3, nvB0, nvB1, nvB2, nvB3);
        }
        TILE(kaA0, kaA1, vA0, vA1, vA2, vA3, false);
        TILE(kaB0, kaB1, vB0, vB1, vB2, vB3, false);
        kaA0 = nkA0; kaA1 = nkA1; kaB0 = nkB0; kaB1 = nkB1;
        vA0 = nvA0; vA1 = nvA1; vA2 = nvA2; vA3 = nvA3;
        vB0 = nvB0; vB1 = nvB1; vB2 = nvB2; vB3 = nvB3;
    }
    // tail: one unmasked 16-tile (qt odd), then the diagonal 16-tile
    if (qt & 1) {
        LOADK(qt - 1, kaA0, kaA1); LOADV(qt - 1, vA0, vA1, vA2, vA3);
        TILE(kaA0, kaA1, vA0, vA1, vA2, vA3, false);
    }
    {
        LOADK(qt, kaB0, kaB1); LOADV(qt, vB0, vB1, vB2, vB3);
        TILE(kaB0, kaB1, vB0, vB1, vB2, vB3, true);
    }
#undef TILE
#undef LOADK
#undef LOADV

    float lt = l + __shfl_xor(l, 16);
    lt += __shfl_xor(lt, 32);
    const float inv = 1.0f / lt;                   // valid at q = c (all lanes)
    const int b = bh / N_HEADS, h = bh % N_HEADS;
    u16* orow = ob + ((size_t)b * SEQ + q0) * D_MODEL + h * 64 + c;
    #pragma unroll
    for (int r = 0; r < 4; ++r) {
        const float iv = __shfl(inv, rbase + r);
        u16* pr = orow + (size_t)(rbase + r) * D_MODEL;
        pr[0]  = f2bf(o0[r] * iv);
        pr[16] = f2bf(o1[r] * iv);
        pr[32] = f2bf(o2[r] * iv);
        pr[48] = f2bf(o3[r] * iv);
    }
}

// ---------------------------------------------------------------------------
extern "C" void kernel_launch(void* const* d_in, const int* in_sizes, int n_in,
                              void* d_out, int out_size, void* d_ws, size_t ws_size,
                              hipStream_t stream)
{
    const float* x      = (const float*)d_in[0];
    // d_in[1] = mask: exactly triu(k=1) causal; applied analytically in-kernel.
    const float* W_qkv  = (const float*)d_in[2];
    const float* b_qkv  = (const float*)d_in[3];
    const float* W_proj = (const float*)d_in[4];
    const float* b_proj = (const float*)d_in[5];
    float* out = (float*)d_out;

    const int nX = BATCH * SEQ * D_MODEL;          // 3,145,728
    const int nWq = 3 * D_MODEL * D_MODEL;         // 1,769,472
    const int nWp = D_MODEL * D_MODEL;             // 589,824
    u16* xb  = (u16*)d_ws;
    u16* wqb = xb + nX;
    u16* wpb = wqb + nWq;
    u16* qbf = wpb + nWp;
    u16* kbf = qbf + nX;
    u16* vtb = kbf + nX;
    u16* ao  = vtb + nX;                           // bf16 [B,T,C]

    // 0) fp32 -> bf16 for x, W_qkv, W_proj
    const int tot4 = (nX + nWq + nWp) / 4;
    cvt3_kernel<<<(tot4 + 255) / 256, 256, 0, stream>>>(x, xb, nX, W_qkv, wqb, nWq,
                                                        W_proj, wpb, nWp);

    // 1) qkv = x @ W_qkv^T + b -> bf16 q(scaled)/k [B,H,T,64], V^T [B,H,64,T]
    mfma_gemm_kernel<128, 128, 0><<<dim3(32, 18), 256, 0, stream>>>(
        xb, wqb, b_qkv, nullptr, qbf, kbf, vtb, BATCH * SEQ, 3 * D_MODEL, D_MODEL);

    // 2) causal MFMA flash attention -> ao bf16 [B,T,C]
    mfma_attn_kernel<<<dim3(SEQ / 16, BATCH * N_HEADS), 64, 0, stream>>>(qbf, kbf, vtb, ao);

    // 3) out = ao @ W_proj^T + b (fp32 out)
    mfma_gemm_kernel<128, 64, 1><<<dim3(32, 12), 256, 0, stream>>>(
        ao, wpb, b_proj, out, nullptr, nullptr, nullptr, BATCH * SEQ, D_MODEL, D_MODEL);
}

// Round 5
// 213.653 us; speedup vs baseline: 6.7282x; 1.4089x over previous
//
#include <hip/hip_runtime.h>
#include <hip/hip_bf16.h>
#include <cstdint>

#define D_MODEL 768
#define N_HEADS 12
#define D_HEAD  64
#define BATCH   2
#define SEQ     2048
// (1/sqrt(64)) * log2(e): QK^T scores land directly in log2 domain (exp2 softmax)
#define SCALE_Q 0.18033688011112042f

typedef float f32x4 __attribute__((ext_vector_type(4)));
typedef short s16x8 __attribute__((ext_vector_type(8)));
typedef short s16x4 __attribute__((ext_vector_type(4)));
typedef unsigned short u16;

static __device__ __forceinline__ u16 f2bf(float f) {
    union { float f; unsigned int u; } c; c.f = f;
    unsigned int u = c.u;
    u += 0x7fffu + ((u >> 16) & 1u);            // RNE
    return (u16)(u >> 16);
}

static __device__ __forceinline__ f32x4 mfma16x32(s16x8 a, s16x8 b, f32x4 c) {
    return __builtin_amdgcn_mfma_f32_16x16x32_bf16(a, b, c, 0, 0, 0);
}
static __device__ __forceinline__ f32x4 mfma16x16(s16x4 a, s16x4 b, f32x4 c) {
#if __has_builtin(__builtin_amdgcn_mfma_f32_16x16x16bf16_1k)
    return __builtin_amdgcn_mfma_f32_16x16x16bf16_1k(a, b, c, 0, 0, 0);
#else
    asm volatile("v_mfma_f32_16x16x16_bf16 %0, %1, %2, %0" : "+v"(c) : "v"(a), "v"(b));
    return c;
#endif
}
// async global->LDS, 16B per lane; LDS dest must be linear in lane order.
static __device__ __forceinline__ void gload_lds16(const void* g, void* l) {
    __builtin_amdgcn_global_load_lds(
        (const __attribute__((address_space(1))) unsigned int*)g,
        (__attribute__((address_space(3))) unsigned int*)l, 16, 0, 0);
}

// ---------------------------------------------------------------------------
// fp32 -> bf16 convert for x, W_qkv, W_proj
// ---------------------------------------------------------------------------
__global__ __launch_bounds__(256)
void cvt3_kernel(const float* __restrict__ s0, u16* __restrict__ d0, int n0,
                 const float* __restrict__ s1, u16* __restrict__ d1, int n1,
                 const float* __restrict__ s2, u16* __restrict__ d2, int n2)
{
    const int idx4 = (blockIdx.x * 256 + threadIdx.x) * 4;
    const float* s; u16* d; int local;
    if (idx4 < n0)           { s = s0; d = d0; local = idx4; }
    else if (idx4 < n0 + n1) { s = s1; d = d1; local = idx4 - n0; }
    else if (idx4 < n0 + n1 + n2) { s = s2; d = d2; local = idx4 - n0 - n1; }
    else return;
    float4 v = *(const float4*)(s + local);
    ushort4 o;
    o.x = f2bf(v.x); o.y = f2bf(v.y); o.z = f2bf(v.z); o.w = f2bf(v.w);
    *(ushort4*)(d + local) = o;
}

// ---------------------------------------------------------------------------
// bf16 MFMA GEMM (NT): C[M,N] = A[M,K] @ B[N,K]^T + bias[N]   (unchanged, passing)
// ---------------------------------------------------------------------------
template<int BM, int BN, int MODE>
__global__ __launch_bounds__(256)
void mfma_gemm_kernel(const u16* __restrict__ A, const u16* __restrict__ Bw,
                      const float* __restrict__ bias,
                      float* __restrict__ outf,
                      u16* __restrict__ qo, u16* __restrict__ ko, u16* __restrict__ vt,
                      int M, int N, int K)
{
    constexpr int BK = 32;
    __shared__ u16 As[BM * BK];
    __shared__ u16 Bs[BN * BK];
    const int tid = threadIdx.x;
    const int wave = tid >> 6, lane = tid & 63;
    const int wr = wave >> 1, wc = wave & 1;
    constexpr int WM = BM / 2, WN = BN / 2, FI = WM / 16, FJ = WN / 16;
    const int g = lane >> 4, c = lane & 15;
    const int bm = blockIdx.x * BM, bn = blockIdx.y * BN;

    f32x4 acc[FI][FJ] = {};

    constexpr int IA = (BM * BK * 2) / (256 * 16);
    constexpr int IB = (BN * BK * 2) / (256 * 16);

    const u16* asrc[IA]; const u16* bsrc[IB];
    #pragma unroll
    for (int i = 0; i < IA; ++i) {
        const int idx = tid + i * 256;
        const int row = idx >> 2, kc = idx & 3;
        const int kcs = kc ^ ((row >> 1) & 3);
        asrc[i] = A + (size_t)(bm + row) * K + kcs * 8;
    }
    #pragma unroll
    for (int i = 0; i < IB; ++i) {
        const int idx = tid + i * 256;
        const int row = idx >> 2, kc = idx & 3;
        const int kcs = kc ^ ((row >> 1) & 3);
        bsrc[i] = Bw + (size_t)(bn + row) * K + kcs * 8;
    }
    const int gsw = g ^ ((c >> 1) & 3);

    for (int k0 = 0; k0 < K; k0 += BK) {
        if (k0) __syncthreads();
        #pragma unroll
        for (int i = 0; i < IA; ++i) gload_lds16(asrc[i] + k0, &As[(tid + i * 256) * 8]);
        #pragma unroll
        for (int i = 0; i < IB; ++i) gload_lds16(bsrc[i] + k0, &Bs[(tid + i * 256) * 8]);
        __syncthreads();

        s16x8 af[FI], bfr[FJ];
        #pragma unroll
        for (int i = 0; i < FI; ++i)
            af[i] = *(const s16x8*)&As[(wr * WM + i * 16 + c) * BK + gsw * 8];
        #pragma unroll
        for (int j = 0; j < FJ; ++j)
            bfr[j] = *(const s16x8*)&Bs[(wc * WN + j * 16 + c) * BK + gsw * 8];
        #pragma unroll
        for (int i = 0; i < FI; ++i)
            #pragma unroll
            for (int j = 0; j < FJ; ++j)
                acc[i][j] = mfma16x32(af[i], bfr[j], acc[i][j]);
    }

    if (MODE == 1) {
        #pragma unroll
        for (int j = 0; j < FJ; ++j) {
            const int col = bn + wc * WN + j * 16 + c;
            const float bv = bias[col];
            #pragma unroll
            for (int i = 0; i < FI; ++i) {
                const int row0 = bm + wr * WM + i * 16 + g * 4;
                #pragma unroll
                for (int r = 0; r < 4; ++r)
                    outf[(size_t)(row0 + r) * N + col] = acc[i][j][r] + bv;
            }
        }
    } else {
        const int which = bn / D_MODEL;
        #pragma unroll
        for (int j = 0; j < FJ; ++j) {
            const int gcol = bn + wc * WN + j * 16 + c;
            const float bv = bias[gcol];
            const int scol = gcol - which * D_MODEL;
            const int h = scol >> 6, d = scol & 63;
            if (which == 2) {
                #pragma unroll
                for (int i = 0; i < FI; ++i) {
                    const int row0 = bm + wr * WM + i * 16 + g * 4;
                    const int b = row0 >> 11, t = row0 & 2047;
                    ushort4 pv;
                    pv.x = f2bf(acc[i][j][0] + bv);
                    pv.y = f2bf(acc[i][j][1] + bv);
                    pv.z = f2bf(acc[i][j][2] + bv);
                    pv.w = f2bf(acc[i][j][3] + bv);
                    *(ushort4*)(vt + ((size_t)(b * N_HEADS + h) * 64 + d) * SEQ + t) = pv;
                }
            } else {
                u16* dst = (which == 0) ? qo : ko;
                const float sc = (which == 0) ? SCALE_Q : 1.0f;  // q in log2-domain units
                #pragma unroll
                for (int i = 0; i < FI; ++i) {
                    const int row0 = bm + wr * WM + i * 16 + g * 4;
                    const int b = row0 >> 11, t = row0 & 2047;
                    #pragma unroll
                    for (int r = 0; r < 4; ++r)
                        dst[(((size_t)(b * N_HEADS + h) * SEQ + t + r) << 6) + d] =
                            f2bf((acc[i][j][r] + bv) * sc);
                }
            }
        }
    }
}

// ---------------------------------------------------------------------------
// MFMA flash attention (round-3 body, known-pass). Changes this round ONLY:
//  (a) balanced 1-D grid: qt pairing so consecutive blocks sum to ~constant
//      work -> no heavy-CU tail;
//  (b) exp2-domain softmax (log2e folded into q scale), plain exp2f().
// Swapped QK^T: lane(g,c) holds P[q=c][kv=g*4+r] == PV A-frag. Per-lane m,
// per-lane partial l, __any-gated rare rescale. KVBLK=32 reg-prefetch.
// ---------------------------------------------------------------------------
__global__ __launch_bounds__(64)
void mfma_attn_kernel(const u16* __restrict__ qb, const u16* __restrict__ kb,
                      const u16* __restrict__ vtb, u16* __restrict__ ob)
{
    const int lane = threadIdx.x;
    const int blk = blockIdx.x;
    const int bh = blk % (BATCH * N_HEADS);
    const int qidx = blk / (BATCH * N_HEADS);
    constexpr int NT = SEQ / 16;
    const int qt = (qidx & 1) ? (NT - 1 - (qidx >> 1)) : (qidx >> 1);  // balanced pairing

    const int g = lane >> 4, c = lane & 15;
    const int rbase = g << 2;          // kv-row base in-tile; also o-row base
    const int q0 = qt << 4;

    const u16* qrow = qb + ((size_t)bh * SEQ + q0 + c) * 64 + g * 8;
    const s16x8 qa0 = *(const s16x8*)(qrow);
    const s16x8 qa1 = *(const s16x8*)(qrow + 32);

    const u16* kbase = kb + (size_t)bh * SEQ * 64 + c * 64 + g * 8;
    const u16* vbase = vtb + ((size_t)bh * 64 + c) * SEQ + g * 4;

    f32x4 o0 = {0,0,0,0}, o1 = {0,0,0,0}, o2 = {0,0,0,0}, o3 = {0,0,0,0};
    float m = 0.f, l = 0.f;

#define LOADK(t16, KA0, KA1) { const u16* kp = kbase + (size_t)(t16) * (16 * 64); \
    KA0 = *(const s16x8*)kp; KA1 = *(const s16x8*)(kp + 32); }
#define LOADV(t16, V0, V1, V2, V3) { const u16* vp = vbase + (t16) * 16;          \
    V0 = *(const s16x4*)vp;              V1 = *(const s16x4*)(vp + 16 * SEQ);     \
    V2 = *(const s16x4*)(vp + 32 * SEQ); V3 = *(const s16x4*)(vp + 48 * SEQ); }

#define TILE(KA0, KA1, V0, V1, V2, V3, MASKED) {                                  \
    f32x4 sa = {0,0,0,0}, sb = {0,0,0,0};                                         \
    sa = mfma16x32(KA0, qa0, sa);                                                 \
    sb = mfma16x32(KA1, qa1, sb);                                                 \
    f32x4 s = sa + sb;                                                            \
    if (MASKED) {                                                                 \
        if (rbase + 0 > c) s[0] = -1e30f;                                         \
        if (rbase + 1 > c) s[1] = -1e30f;                                         \
        if (rbase + 2 > c) s[2] = -1e30f;                                         \
        if (rbase + 3 > c) s[3] = -1e30f;                                         \
    }                                                                             \
    float pmax = fmaxf(fmaxf(s[0], s[1]), fmaxf(s[2], s[3]));                     \
    if (__any(pmax > m + 8.f)) {               /* rare: full rescale */           \
        pmax = fmaxf(pmax, __shfl_xor(pmax, 16));                                 \
        pmax = fmaxf(pmax, __shfl_xor(pmax, 32));                                 \
        const float mn = fmaxf(m, pmax);                                          \
        const float scr = exp2f(m - mn);                                          \
        l *= scr;                                                                 \
        f32x4 scv;                                                                \
        scv[0] = __shfl(scr, rbase + 0);                                          \
        scv[1] = __shfl(scr, rbase + 1);                                          \
        scv[2] = __shfl(scr, rbase + 2);                                          \
        scv[3] = __shfl(scr, rbase + 3);                                          \
        o0 *= scv; o1 *= scv; o2 *= scv; o3 *= scv;                               \
        m = mn;                                                                   \
    }                                                                             \
    const float p0 = exp2f(s[0] - m), p1 = exp2f(s[1] - m);                       \
    const float p2 = exp2f(s[2] - m), p3 = exp2f(s[3] - m);                       \
    l += (p0 + p1) + (p2 + p3);                                                   \
    s16x4 pa;                                                                     \
    pa[0] = (short)f2bf(p0); pa[1] = (short)f2bf(p1);                             \
    pa[2] = (short)f2bf(p2); pa[3] = (short)f2bf(p3);                             \
    o0 = mfma16x16(pa, V0, o0);                                                   \
    o1 = mfma16x16(pa, V1, o1);                                                   \
    o2 = mfma16x16(pa, V2, o2);                                                   \
    o3 = mfma16x16(pa, V3, o3);                                                   \
}

    const int nfull = qt >> 1;                     // full 32-kv chunks
    s16x8 kaA0, kaA1, kaB0, kaB1, nkA0, nkA1, nkB0, nkB1;
    s16x4 vA0, vA1, vA2, vA3, vB0, vB1, vB2, vB3;
    s16x4 nvA0, nvA1, nvA2, nvA3, nvB0, nvB1, nvB2, nvB3;

    if (nfull > 0) {
        LOADK(0, kaA0, kaA1); LOADV(0, vA0, vA1, vA2, vA3);
        LOADK(1, kaB0, kaB1); LOADV(1, vB0, vB1, vB2, vB3);
    }
    for (int ch = 0; ch < nfull; ++ch) {
        if (ch + 1 < nfull) {                      // prefetch next chunk
            LOADK(2 * ch + 2, nkA0, nkA1); LOADV(2 * ch + 2, nvA0, nvA1, nvA2, nvA3);
            LOADK(2 * ch + 3, nkB0, nkB1); LOADV(2 * ch + 3, nvB0, nvB1, nvB2, nvB3);
        }
        TILE(kaA0, kaA1, vA0, vA1, vA2, vA3, false);
        TILE(kaB0, kaB1, vB0, vB1, vB2, vB3, false);
        kaA0 = nkA0; kaA1 = nkA1; kaB0 = nkB0; kaB1 = nkB1;
        vA0 = nvA0; vA1 = nvA1; vA2 = nvA2; vA3 = nvA3;
        vB0 = nvB0; vB1 = nvB1; vB2 = nvB2; vB3 = nvB3;
    }
    // tail: one unmasked 16-tile (qt odd), then the diagonal 16-tile
    if (qt & 1) {
        LOADK(qt - 1, kaA0, kaA1); LOADV(qt - 1, vA0, vA1, vA2, vA3);
        TILE(kaA0, kaA1, vA0, vA1, vA2, vA3, false);
    }
    {
        LOADK(qt, kaB0, kaB1); LOADV(qt, vB0, vB1, vB2, vB3);
        TILE(kaB0, kaB1, vB0, vB1, vB2, vB3, true);
    }
#undef TILE
#undef LOADK
#undef LOADV

    float lt = l + __shfl_xor(l, 16);
    lt += __shfl_xor(lt, 32);
    const float inv = 1.0f / lt;                   // valid at q = c (all lanes)
    const int b = bh / N_HEADS, h = bh % N_HEADS;
    u16* orow = ob + ((size_t)b * SEQ + q0) * D_MODEL + h * 64 + c;
    #pragma unroll
    for (int r = 0; r < 4; ++r) {
        const float iv = __shfl(inv, rbase + r);
        u16* pr = orow + (size_t)(rbase + r) * D_MODEL;
        pr[0]  = f2bf(o0[r] * iv);
        pr[16] = f2bf(o1[r] * iv);
        pr[32] = f2bf(o2[r] * iv);
        pr[48] = f2bf(o3[r] * iv);
    }
}

// ---------------------------------------------------------------------------
extern "C" void kernel_launch(void* const* d_in, const int* in_sizes, int n_in,
                              void* d_out, int out_size, void* d_ws, size_t ws_size,
                              hipStream_t stream)
{
    const float* x      = (const float*)d_in[0];
    // d_in[1] = mask: exactly triu(k=1) causal; applied analytically in-kernel.
    const float* W_qkv  = (const float*)d_in[2];
    const float* b_qkv  = (const float*)d_in[3];
    const float* W_proj = (const float*)d_in[4];
    const float* b_proj = (const float*)d_in[5];
    float* out = (float*)d_out;

    const int nX = BATCH * SEQ * D_MODEL;
    const int nWq = 3 * D_MODEL * D_MODEL;
    const int nWp = D_MODEL * D_MODEL;
    u16* xb  = (u16*)d_ws;
    u16* wqb = xb + nX;
    u16* wpb = wqb + nWq;
    u16* qbf = wpb + nWp;
    u16* kbf = qbf + nX;
    u16* vtb = kbf + nX;
    u16* ao  = vtb + nX;                // bf16 [B,T,C]

    const int tot4 = (nX + nWq + nWp) / 4;
    cvt3_kernel<<<(tot4 + 255) / 256, 256, 0, stream>>>(x, xb, nX, W_qkv, wqb, nWq,
                                                        W_proj, wpb, nWp);

    mfma_gemm_kernel<128, 128, 0><<<dim3(32, 18), 256, 0, stream>>>(
        xb, wqb, b_qkv, nullptr, qbf, kbf, vtb, BATCH * SEQ, 3 * D_MODEL, D_MODEL);

    mfma_attn_kernel<<<dim3((SEQ / 16) * BATCH * N_HEADS), 64, 0, stream>>>(qbf, kbf, vtb, ao);

    mfma_gemm_kernel<128, 64, 1><<<dim3(32, 12), 256, 0, stream>>>(
        ao, wpb, b_proj, out, nullptr, nullptr, nullptr, BATCH * SEQ, D_MODEL, D_MODEL);
}